// Round 1
// baseline (1724.732 us; speedup 1.0000x reference)
//
#include <hip/hip_runtime.h>
#include <hip/hip_bf16.h>

#define N_NODES 100000
#define N_EDGES 1600000
#define N_GRAPHS 1024
#define BSZ 1024
#define EPS 1e-5f

// ---------------- workspace layout (float offsets) ----------------
// zeroed-every-call region:
#define WS_BNAGG   0          // 256   (sum[128], sumsq[128]) of agg
#define WS_SUMS    256        // 1024*128 pooled sums
#define WS_CNT     131328     // 1024
#define WS_STATS1  132352     // 128 (t1: sum[64], sumsq[64])
#define WS_STATS2  132480     // 128 (t2)
#define WS_STATS4  132608     // 512 (t4: sum[256], sumsq[256])
#define WS_STATS5  133120     // 128 (t5)
#define WS_DEG     133248     // 100000 (edge-dst counts; total deg = this + 1)
#define WS_ZTOTAL  233248
// written-before-read region:
#define WS_DIS     233248     // 100000
#define WS_SCALE1  333248     // 128
#define WS_SHIFT1  333376     // 128
#define WS_H       333504     // 100000*128
#define WS_AGG     13133504   // 100000*128
#define WS_T1      25933504   // 1024*64
#define WS_T2      25999040   // 1024*64
#define WS_T4      26064576   // 1024*256
#define WS_T5      26326720   // 1024*64
// total = 26392256 floats = ~105.6 MB

__global__ void zero_kernel(float* __restrict__ p, int n) {
    int i = blockIdx.x * blockDim.x + threadIdx.x;
    int stride = gridDim.x * blockDim.x;
    for (; i < n; i += stride) p[i] = 0.0f;
}

// h[100000,128] = gnn_x[100000,64] @ W_gcn[64,128]
__global__ __launch_bounds__(256) void gemm_h_kernel(const float* __restrict__ A,
                                                     const float* __restrict__ W,
                                                     float* __restrict__ H) {
    __shared__ float Ws[64 * 128];
    __shared__ float As[16 * 64];
    int tid = threadIdx.x;
    const float4* W4 = (const float4*)W;
    float4* Ws4 = (float4*)Ws;
#pragma unroll
    for (int i = 0; i < 8; ++i) Ws4[tid + i * 256] = W4[tid + i * 256];
    int row0 = blockIdx.x * 16;
    ((float4*)As)[tid] = ((const float4*)(A + (size_t)row0 * 64))[tid];
    __syncthreads();
    int tx = tid & 31;   // 4-col group
    int ty = tid >> 5;   // row pair
    int r0 = ty * 2;
    float acc[2][4] = {};
#pragma unroll
    for (int k = 0; k < 64; ++k) {
        float a0 = As[r0 * 64 + k];
        float a1 = As[(r0 + 1) * 64 + k];
        float4 w = Ws4[k * 32 + tx];
        acc[0][0] += a0 * w.x; acc[0][1] += a0 * w.y; acc[0][2] += a0 * w.z; acc[0][3] += a0 * w.w;
        acc[1][0] += a1 * w.x; acc[1][1] += a1 * w.y; acc[1][2] += a1 * w.z; acc[1][3] += a1 * w.w;
    }
#pragma unroll
    for (int rr = 0; rr < 2; ++rr) {
        float4 v = make_float4(acc[rr][0], acc[rr][1], acc[rr][2], acc[rr][3]);
        ((float4*)(H + (size_t)(row0 + r0 + rr) * 128))[tx] = v;
    }
}

__global__ void deg_count_kernel(const int* __restrict__ dst, float* __restrict__ deg) {
    int i = blockIdx.x * blockDim.x + threadIdx.x;
    if (i < N_EDGES) unsafeAtomicAdd(&deg[dst[i]], 1.0f);
}

// agg = h/deg_total + b_gcn (self-loop term), dis = rsqrt(deg_total)
__global__ void agg_init_kernel(const float* __restrict__ H, const float* __restrict__ deg,
                                const float* __restrict__ b_gcn, float* __restrict__ agg,
                                float* __restrict__ dis) {
    int t = blockIdx.x * 256 + threadIdx.x;
    int node = t >> 6;
    int lane = t & 63;
    if (node >= N_NODES) return;
    float dtot = deg[node] + 1.0f;
    int f = lane * 2;
    float2 hh = *(const float2*)(H + (size_t)node * 128 + f);
    float2 bb = *(const float2*)(b_gcn + f);
    float inv = 1.0f / dtot;
    float2 o; o.x = hh.x * inv + bb.x; o.y = hh.y * inv + bb.y;
    *(float2*)(agg + (size_t)node * 128 + f) = o;
    if (lane == 0) dis[node] = rsqrtf(dtot);
}

__global__ void edge_scatter_kernel(const int* __restrict__ ei, const float* __restrict__ H,
                                    const float* __restrict__ dis, float* __restrict__ agg) {
    long long t = (long long)blockIdx.x * 256 + threadIdx.x;
    int e = (int)(t >> 6);
    int lane = (int)(t & 63);
    if (e >= N_EDGES) return;
    int s = ei[e];
    int d = ei[N_EDGES + e];
    float n = dis[s] * dis[d];
    int f = lane * 2;
    float2 hh = *(const float2*)(H + (size_t)s * 128 + f);
    unsafeAtomicAdd(agg + (size_t)d * 128 + f, hh.x * n);
    unsafeAtomicAdd(agg + (size_t)d * 128 + f + 1, hh.y * n);
}

__global__ __launch_bounds__(256) void bnagg_stats_kernel(const float* __restrict__ agg,
                                                          float* __restrict__ stats) {
    __shared__ float4 ls[256];
    int tid = threadIdx.x;
    int lane = tid & 63;
    int grp = tid >> 6;
    int f = lane * 2;
    float2 s = {0.f, 0.f}, sq = {0.f, 0.f};
    for (int r = blockIdx.x * 4 + grp; r < N_NODES; r += gridDim.x * 4) {
        float2 a = *(const float2*)(agg + (size_t)r * 128 + f);
        s.x += a.x; s.y += a.y;
        sq.x += a.x * a.x; sq.y += a.y * a.y;
    }
    ls[tid] = make_float4(s.x, s.y, sq.x, sq.y);
    __syncthreads();
    if (tid < 64) {
        float4 v = ls[tid];
        float4 b = ls[tid + 64], c = ls[tid + 128], d = ls[tid + 192];
        v.x += b.x + c.x + d.x;
        v.y += b.y + c.y + d.y;
        v.z += b.z + c.z + d.z;
        v.w += b.w + c.w + d.w;
        unsafeAtomicAdd(&stats[f], v.x);
        unsafeAtomicAdd(&stats[f + 1], v.y);
        unsafeAtomicAdd(&stats[128 + f], v.z);
        unsafeAtomicAdd(&stats[128 + f + 1], v.w);
    }
}

__global__ void bn1_fold_kernel(const float* __restrict__ stats, const float* __restrict__ g1,
                                const float* __restrict__ be1, float* __restrict__ scale1,
                                float* __restrict__ shift1) {
    int f = threadIdx.x;
    float m = stats[f] * (1.0f / N_NODES);
    float var = stats[128 + f] * (1.0f / N_NODES) - m * m;
    float sc = g1[f] * rsqrtf(var + EPS);
    scale1[f] = sc;
    shift1[f] = be1[f] - m * sc;
}

__global__ void pool_scatter_kernel(const float* __restrict__ agg, const int* __restrict__ batch,
                                    const float* __restrict__ scale1, const float* __restrict__ shift1,
                                    float* __restrict__ sums, float* __restrict__ cnt) {
    int t = blockIdx.x * 256 + threadIdx.x;
    int node = t >> 6;
    int lane = t & 63;
    if (node >= N_NODES) return;
    int b = batch[node];
    int f = lane * 2;
    float2 a = *(const float2*)(agg + (size_t)node * 128 + f);
    float2 sc = *(const float2*)(scale1 + f);
    float2 sh = *(const float2*)(shift1 + f);
    float zx = fmaxf(a.x * sc.x + sh.x, 0.f);
    float zy = fmaxf(a.y * sc.y + sh.y, 0.f);
    unsafeAtomicAdd(sums + (size_t)b * 128 + f, zx);
    unsafeAtomicAdd(sums + (size_t)b * 128 + f + 1, zy);
    if (lane == 0) unsafeAtomicAdd(&cnt[b], 1.0f);
}

// t1 = pooled @ W_lin1 + b ; stats1 += (sum, sumsq)
__global__ __launch_bounds__(256) void lin1_kernel(const float* __restrict__ sums,
                                                   const float* __restrict__ cnt,
                                                   const float* __restrict__ W,
                                                   const float* __restrict__ bias,
                                                   float* __restrict__ t1,
                                                   float* __restrict__ stats1) {
    __shared__ float ls[256], ls2[256];
    int tid = threadIdx.x;
    int r = blockIdx.x * 4 + (tid >> 6);
    int c = tid & 63;
    float invc = 1.0f / fmaxf(cnt[r], 1.0f);
    float acc = bias[c];
    const float* srow = sums + (size_t)r * 128;
#pragma unroll 8
    for (int k = 0; k < 128; ++k)
        acc += (srow[k] * invc) * W[k * 64 + c];
    t1[r * 64 + c] = acc;
    ls[tid] = acc; ls2[tid] = acc * acc;
    __syncthreads();
    if (tid < 64) {
        float s = ls[tid] + ls[tid + 64] + ls[tid + 128] + ls[tid + 192];
        float q = ls2[tid] + ls2[tid + 64] + ls2[tid + 128] + ls2[tid + 192];
        unsafeAtomicAdd(&stats1[c], s);
        unsafeAtomicAdd(&stats1[64 + c], q);
    }
}

// t2 = relu(bn(t1; g2,be2)) @ W_lin2 + b ; stats2
__global__ __launch_bounds__(256) void lin2_kernel(const float* __restrict__ t1,
                                                   const float* __restrict__ stats1,
                                                   const float* __restrict__ g,
                                                   const float* __restrict__ be,
                                                   const float* __restrict__ W,
                                                   const float* __restrict__ bias,
                                                   float* __restrict__ t2,
                                                   float* __restrict__ stats2) {
    __shared__ float sc[64], sh[64];
    __shared__ float ls[256], ls2[256];
    int tid = threadIdx.x;
    if (tid < 64) {
        float m = stats1[tid] * (1.0f / BSZ);
        float var = stats1[64 + tid] * (1.0f / BSZ) - m * m;
        float s = g[tid] * rsqrtf(var + EPS);
        sc[tid] = s; sh[tid] = be[tid] - m * s;
    }
    __syncthreads();
    int r = blockIdx.x * 4 + (tid >> 6);
    int c = tid & 63;
    float acc = bias[c];
    const float* row = t1 + (size_t)r * 64;
#pragma unroll 8
    for (int k = 0; k < 64; ++k) {
        float z = fmaxf(row[k] * sc[k] + sh[k], 0.f);
        acc += z * W[k * 64 + c];
    }
    t2[r * 64 + c] = acc;
    ls[tid] = acc; ls2[tid] = acc * acc;
    __syncthreads();
    if (tid < 64) {
        float s = ls[tid] + ls[tid + 64] + ls[tid + 128] + ls[tid + 192];
        float q = ls2[tid] + ls2[tid + 64] + ls2[tid + 128] + ls2[tid + 192];
        unsafeAtomicAdd(&stats2[c], s);
        unsafeAtomicAdd(&stats2[64 + c], q);
    }
}

// t4 = concat(x, bn(t2;g3,be3)[masks]) @ W_fc1 + b ; stats4
__global__ __launch_bounds__(1024) void fc1_kernel(const float* __restrict__ x,
                                                   const int* __restrict__ masks,
                                                   const float* __restrict__ t2,
                                                   const float* __restrict__ stats2,
                                                   const float* __restrict__ g3,
                                                   const float* __restrict__ be3,
                                                   const float* __restrict__ W,
                                                   const float* __restrict__ bias,
                                                   float* __restrict__ t4,
                                                   float* __restrict__ stats4) {
    __shared__ float sc[64], sh[64];
    __shared__ float cat[4][128];
    __shared__ float ls[1024], ls2[1024];
    int tid = threadIdx.x;
    if (tid < 64) {
        float m = stats2[tid] * (1.0f / BSZ);
        float var = stats2[64 + tid] * (1.0f / BSZ) - m * m;
        float s = g3[tid] * rsqrtf(var + EPS);
        sc[tid] = s; sh[tid] = be3[tid] - m * s;
    }
    __syncthreads();
    int r0 = blockIdx.x * 4;
    if (tid < 512) {
        int i = tid >> 7;
        int k = tid & 127;
        int r = r0 + i;
        float v;
        if (k < 64) {
            v = x[r * 64 + k];
        } else {
            int mrow = masks[r];
            int kk = k - 64;
            v = t2[mrow * 64 + kk] * sc[kk] + sh[kk];
        }
        cat[i][k] = v;
    }
    __syncthreads();
    int i = tid >> 8;
    int c = tid & 255;
    float acc = bias[c];
#pragma unroll 8
    for (int k = 0; k < 128; ++k)
        acc += cat[i][k] * W[k * 256 + c];
    t4[(size_t)(r0 + i) * 256 + c] = acc;
    ls[tid] = acc; ls2[tid] = acc * acc;
    __syncthreads();
    if (tid < 256) {
        float s = ls[tid] + ls[tid + 256] + ls[tid + 512] + ls[tid + 768];
        float q = ls2[tid] + ls2[tid + 256] + ls2[tid + 512] + ls2[tid + 768];
        unsafeAtomicAdd(&stats4[c], s);
        unsafeAtomicAdd(&stats4[256 + c], q);
    }
}

// t5 = (relu(bn(t4;g4,be4))^2) @ W_fc2 + b ; stats5
__global__ __launch_bounds__(256) void fc2_kernel(const float* __restrict__ t4,
                                                  const float* __restrict__ stats4,
                                                  const float* __restrict__ g4,
                                                  const float* __restrict__ be4,
                                                  const float* __restrict__ W,
                                                  const float* __restrict__ bias,
                                                  float* __restrict__ t5,
                                                  float* __restrict__ stats5) {
    __shared__ float sc[256], sh[256];
    __shared__ float ls[256], ls2[256];
    int tid = threadIdx.x;
    {
        float m = stats4[tid] * (1.0f / BSZ);
        float var = stats4[256 + tid] * (1.0f / BSZ) - m * m;
        float s = g4[tid] * rsqrtf(var + EPS);
        sc[tid] = s; sh[tid] = be4[tid] - m * s;
    }
    __syncthreads();
    int r = blockIdx.x * 4 + (tid >> 6);
    int c = tid & 63;
    float acc = bias[c];
    const float* row = t4 + (size_t)r * 256;
#pragma unroll 8
    for (int k = 0; k < 256; ++k) {
        float z = fmaxf(row[k] * sc[k] + sh[k], 0.f);
        z *= z;
        acc += z * W[k * 64 + c];
    }
    t5[r * 64 + c] = acc;
    ls[tid] = acc; ls2[tid] = acc * acc;
    __syncthreads();
    if (tid < 64) {
        float s = ls[tid] + ls[tid + 64] + ls[tid + 128] + ls[tid + 192];
        float q = ls2[tid] + ls2[tid + 64] + ls2[tid + 128] + ls2[tid + 192];
        unsafeAtomicAdd(&stats5[c], s);
        unsafeAtomicAdd(&stats5[64 + c], q);
    }
}

// out = ((relu(bn(t5;g5,be5)))^4) @ W_fc3 + b
__global__ __launch_bounds__(256) void fc3_kernel(const float* __restrict__ t5,
                                                  const float* __restrict__ stats5,
                                                  const float* __restrict__ g5,
                                                  const float* __restrict__ be5,
                                                  const float* __restrict__ W,
                                                  const float* __restrict__ bias,
                                                  float* __restrict__ out) {
    __shared__ float sc[64], sh[64];
    int tid = threadIdx.x;
    if (tid < 64) {
        float m = stats5[tid] * (1.0f / BSZ);
        float var = stats5[64 + tid] * (1.0f / BSZ) - m * m;
        float s = g5[tid] * rsqrtf(var + EPS);
        sc[tid] = s; sh[tid] = be5[tid] - m * s;
    }
    __syncthreads();
    int r = blockIdx.x * 256 + tid;
    float acc = bias[0];
    const float* row = t5 + (size_t)r * 64;
#pragma unroll
    for (int k = 0; k < 64; ++k) {
        float z = fmaxf(row[k] * sc[k] + sh[k], 0.f);
        z = z * z;
        z = z * z;
        acc += z * W[k];
    }
    out[r] = acc;
}

extern "C" void kernel_launch(void* const* d_in, const int* in_sizes, int n_in,
                              void* d_out, int out_size, void* d_ws, size_t ws_size,
                              hipStream_t stream) {
    const float* x      = (const float*)d_in[0];
    const int*   masks  = (const int*)d_in[1];
    const float* gnn_x  = (const float*)d_in[2];
    const int*   ei     = (const int*)d_in[3];
    const int*   gbatch = (const int*)d_in[4];
    const float* W_gcn  = (const float*)d_in[5];
    const float* b_gcn  = (const float*)d_in[6];
    const float* g1     = (const float*)d_in[7];
    const float* be1    = (const float*)d_in[8];
    const float* W_lin1 = (const float*)d_in[9];
    const float* b_lin1 = (const float*)d_in[10];
    const float* g2     = (const float*)d_in[11];
    const float* be2    = (const float*)d_in[12];
    const float* W_lin2 = (const float*)d_in[13];
    const float* b_lin2 = (const float*)d_in[14];
    const float* g3     = (const float*)d_in[15];
    const float* be3    = (const float*)d_in[16];
    const float* W_fc1  = (const float*)d_in[17];
    const float* b_fc1  = (const float*)d_in[18];
    const float* g4     = (const float*)d_in[19];
    const float* be4    = (const float*)d_in[20];
    const float* W_fc2  = (const float*)d_in[21];
    const float* b_fc2  = (const float*)d_in[22];
    const float* g5     = (const float*)d_in[23];
    const float* be5    = (const float*)d_in[24];
    const float* W_fc3  = (const float*)d_in[25];
    const float* b_fc3  = (const float*)d_in[26];

    float* ws = (float*)d_ws;
    float* bnagg  = ws + WS_BNAGG;
    float* sums   = ws + WS_SUMS;
    float* cnt    = ws + WS_CNT;
    float* stats1 = ws + WS_STATS1;
    float* stats2 = ws + WS_STATS2;
    float* stats4 = ws + WS_STATS4;
    float* stats5 = ws + WS_STATS5;
    float* deg    = ws + WS_DEG;
    float* dis    = ws + WS_DIS;
    float* scale1 = ws + WS_SCALE1;
    float* shift1 = ws + WS_SHIFT1;
    float* h      = ws + WS_H;
    float* agg    = ws + WS_AGG;
    float* t1     = ws + WS_T1;
    float* t2     = ws + WS_T2;
    float* t4     = ws + WS_T4;
    float* t5     = ws + WS_T5;
    float* out    = (float*)d_out;

    zero_kernel<<<512, 256, 0, stream>>>(ws, WS_ZTOTAL);
    gemm_h_kernel<<<N_NODES / 16, 256, 0, stream>>>(gnn_x, W_gcn, h);
    deg_count_kernel<<<(N_EDGES + 255) / 256, 256, 0, stream>>>(ei + N_EDGES, deg);
    agg_init_kernel<<<N_NODES * 64 / 256, 256, 0, stream>>>(h, deg, b_gcn, agg, dis);
    edge_scatter_kernel<<<(int)((size_t)N_EDGES * 64 / 256), 256, 0, stream>>>(ei, h, dis, agg);
    bnagg_stats_kernel<<<512, 256, 0, stream>>>(agg, bnagg);
    bn1_fold_kernel<<<1, 128, 0, stream>>>(bnagg, g1, be1, scale1, shift1);
    pool_scatter_kernel<<<N_NODES * 64 / 256, 256, 0, stream>>>(agg, gbatch, scale1, shift1, sums, cnt);
    lin1_kernel<<<256, 256, 0, stream>>>(sums, cnt, W_lin1, b_lin1, t1, stats1);
    lin2_kernel<<<256, 256, 0, stream>>>(t1, stats1, g2, be2, W_lin2, b_lin2, t2, stats2);
    fc1_kernel<<<256, 1024, 0, stream>>>(x, masks, t2, stats2, g3, be3, W_fc1, b_fc1, t4, stats4);
    fc2_kernel<<<256, 256, 0, stream>>>(t4, stats4, g4, be4, W_fc2, b_fc2, t5, stats5);
    fc3_kernel<<<4, 256, 0, stream>>>(t5, stats5, g5, be5, W_fc3, b_fc3, out);
}

// Round 2
// 484.833 us; speedup vs baseline: 3.5574x; 3.5574x over previous
//
#include <hip/hip_runtime.h>
#include <hip/hip_bf16.h>

#define N_NODES 100000
#define N_EDGES 1600000
#define N_GRAPHS 1024
#define BSZ 1024
#define EPS 1e-5f
#define SCAN_NB 391   // ceil(100000/256)

// ---------------- workspace layout (4-byte units) ----------------
// zeroed-every-call region:
#define WS_BNAGG   0          // 256  (sum[128], sumsq[128]) of agg
#define WS_STATS1  256        // 128
#define WS_STATS2  384        // 128
#define WS_STATS4  512        // 512
#define WS_STATS5  1024       // 128
#define WS_DEG     1152       // 100000 int (edge-dst counts; deg_total = this+1)
#define WS_ZTOTAL  101152
// written-before-read region:
#define WS_INCL    101152     // 100096 int (within-block inclusive scan)
#define WS_PARTIAL 201248     // 512 int
#define WS_POFF    201760     // 512 int
#define WS_ROWPTR  202272     // 100001 int (pad to 302276)
#define WS_CURSOR  302276     // 100000 int
#define WS_DIS     402276     // 100000 float
#define WS_CSRC    502276     // 1600000 int (edge src sorted by dst bucket)
#define WS_SCALE1  2102276    // 128
#define WS_SHIFT1  2102404    // 128
#define WS_GSTART  2102532    // 1025 int (pad to 2103560)
#define WS_AGGX    2103560    // 100000*64
#define WS_AGG     8503560    // 100000*128
#define WS_POOLED  21303560   // 1024*128
#define WS_T1      21434632   // 1024*64
#define WS_T2      21500168   // 1024*64
#define WS_T4      21565704   // 1024*256
#define WS_T5      21827848   // 1024*64
// total = 21893384 words = ~87.6 MB

__global__ void zero_kernel(float* __restrict__ p, int n) {
    int i = blockIdx.x * blockDim.x + threadIdx.x;
    int stride = gridDim.x * blockDim.x;
    for (; i < n; i += stride) p[i] = 0.0f;
}

__global__ void deg_count_kernel(const int* __restrict__ dst, int* __restrict__ deg) {
    int i = blockIdx.x * blockDim.x + threadIdx.x;
    if (i < N_EDGES) atomicAdd(&deg[dst[i]], 1);
}

// within-block inclusive scan of deg
__global__ __launch_bounds__(256) void scan1_kernel(const int* __restrict__ deg,
                                                    int* __restrict__ incl,
                                                    int* __restrict__ partial) {
    __shared__ int ls[256];
    int tid = threadIdx.x;
    int i = blockIdx.x * 256 + tid;
    int v = (i < N_NODES) ? deg[i] : 0;
    ls[tid] = v;
    for (int off = 1; off < 256; off <<= 1) {
        __syncthreads();
        int t = (tid >= off) ? ls[tid - off] : 0;
        __syncthreads();
        ls[tid] += t;
    }
    __syncthreads();
    incl[i] = ls[tid];
    if (tid == 255) partial[blockIdx.x] = ls[255];
}

// exclusive scan of 391 block partials (single block)
__global__ __launch_bounds__(512) void scan2_kernel(const int* __restrict__ partial,
                                                    int* __restrict__ poff) {
    __shared__ int ls[512];
    int tid = threadIdx.x;
    int v = (tid < SCAN_NB) ? partial[tid] : 0;
    ls[tid] = v;
    for (int off = 1; off < 512; off <<= 1) {
        __syncthreads();
        int t = (tid >= off) ? ls[tid - off] : 0;
        __syncthreads();
        ls[tid] += t;
    }
    __syncthreads();
    if (tid < SCAN_NB) poff[tid] = ls[tid] - v;
}

// rowptr (exclusive) + cursor copy + dis
__global__ __launch_bounds__(256) void scan3_kernel(const int* __restrict__ deg,
                                                    const int* __restrict__ incl,
                                                    const int* __restrict__ poff,
                                                    int* __restrict__ rowptr,
                                                    int* __restrict__ cursor,
                                                    float* __restrict__ dis) {
    int i = blockIdx.x * 256 + threadIdx.x;
    if (i >= N_NODES) return;
    int d = deg[i];
    int excl = incl[i] - d + poff[blockIdx.x];
    rowptr[i] = excl;
    cursor[i] = excl;
    dis[i] = rsqrtf((float)d + 1.0f);
    if (i == 0) rowptr[N_NODES] = N_EDGES;
}

__global__ void csr_fill_kernel(const int* __restrict__ ei, int* __restrict__ cursor,
                                int* __restrict__ csrc) {
    int e = blockIdx.x * blockDim.x + threadIdx.x;
    if (e >= N_EDGES) return;
    int s = ei[e];
    int d = ei[N_EDGES + e];
    int slot = atomicAdd(&cursor[d], 1);
    csrc[slot] = s;
}

// agg_x[node] = x[node]*dis[node]^2 + sum_{s in in(node)} x[s]*dis[s]*dis[node]
// one wave (64 lanes) per node; lane = feature (GNN_INP = 64)
__global__ __launch_bounds__(256) void gather_aggx_kernel(const float* __restrict__ x,
                                                          const int* __restrict__ rowptr,
                                                          const int* __restrict__ csrc,
                                                          const float* __restrict__ dis,
                                                          float* __restrict__ aggx) {
    int wid = (blockIdx.x * 256 + threadIdx.x) >> 6;
    int lane = threadIdx.x & 63;
    if (wid >= N_NODES) return;
    int start = rowptr[wid];
    int end = rowptr[wid + 1];
    float dd = dis[wid];
    float acc = x[(size_t)wid * 64 + lane] * dd * dd;
    for (int j0 = start; j0 < end; j0 += 64) {
        int cnt = min(64, end - j0);
        int sv = (lane < cnt) ? csrc[j0 + lane] : 0;
        for (int k = 0; k < cnt; ++k) {
            int s = __shfl(sv, k);
            float ns = dis[s] * dd;
            acc += x[(size_t)s * 64 + lane] * ns;
        }
    }
    aggx[(size_t)wid * 64 + lane] = acc;
}

// agg[100000,128] = aggx[100000,64] @ W_gcn[64,128] + b_gcn
__global__ __launch_bounds__(256) void gemm_agg_kernel(const float* __restrict__ A,
                                                       const float* __restrict__ W,
                                                       const float* __restrict__ bias,
                                                       float* __restrict__ AGG) {
    __shared__ float Ws[64 * 128];
    __shared__ float As[16 * 64];
    int tid = threadIdx.x;
    const float4* W4 = (const float4*)W;
    float4* Ws4 = (float4*)Ws;
#pragma unroll
    for (int i = 0; i < 8; ++i) Ws4[tid + i * 256] = W4[tid + i * 256];
    int row0 = blockIdx.x * 16;
    ((float4*)As)[tid] = ((const float4*)(A + (size_t)row0 * 64))[tid];
    __syncthreads();
    int tx = tid & 31;   // float4 col group
    int ty = tid >> 5;   // row pair
    int r0 = ty * 2;
    float4 bb = ((const float4*)bias)[tx];
    float acc[2][4] = {{bb.x, bb.y, bb.z, bb.w}, {bb.x, bb.y, bb.z, bb.w}};
#pragma unroll
    for (int k = 0; k < 64; ++k) {
        float a0 = As[r0 * 64 + k];
        float a1 = As[(r0 + 1) * 64 + k];
        float4 w = Ws4[k * 32 + tx];
        acc[0][0] += a0 * w.x; acc[0][1] += a0 * w.y; acc[0][2] += a0 * w.z; acc[0][3] += a0 * w.w;
        acc[1][0] += a1 * w.x; acc[1][1] += a1 * w.y; acc[1][2] += a1 * w.z; acc[1][3] += a1 * w.w;
    }
#pragma unroll
    for (int rr = 0; rr < 2; ++rr) {
        float4 v = make_float4(acc[rr][0], acc[rr][1], acc[rr][2], acc[rr][3]);
        ((float4*)(AGG + (size_t)(row0 + r0 + rr) * 128))[tx] = v;
    }
}

__global__ __launch_bounds__(256) void bnagg_stats_kernel(const float* __restrict__ agg,
                                                          float* __restrict__ stats) {
    __shared__ float4 ls[256];
    int tid = threadIdx.x;
    int lane = tid & 63;
    int grp = tid >> 6;
    int f = lane * 2;
    float2 s = {0.f, 0.f}, sq = {0.f, 0.f};
    for (int r = blockIdx.x * 4 + grp; r < N_NODES; r += gridDim.x * 4) {
        float2 a = *(const float2*)(agg + (size_t)r * 128 + f);
        s.x += a.x; s.y += a.y;
        sq.x += a.x * a.x; sq.y += a.y * a.y;
    }
    ls[tid] = make_float4(s.x, s.y, sq.x, sq.y);
    __syncthreads();
    if (tid < 64) {
        float4 v = ls[tid];
        float4 b = ls[tid + 64], c = ls[tid + 128], d = ls[tid + 192];
        v.x += b.x + c.x + d.x;
        v.y += b.y + c.y + d.y;
        v.z += b.z + c.z + d.z;
        v.w += b.w + c.w + d.w;
        unsafeAtomicAdd(&stats[f], v.x);
        unsafeAtomicAdd(&stats[f + 1], v.y);
        unsafeAtomicAdd(&stats[128 + f], v.z);
        unsafeAtomicAdd(&stats[128 + f + 1], v.w);
    }
}

__global__ void bn1_fold_kernel(const float* __restrict__ stats, const float* __restrict__ g1,
                                const float* __restrict__ be1, float* __restrict__ scale1,
                                float* __restrict__ shift1) {
    int f = threadIdx.x;
    float m = stats[f] * (1.0f / N_NODES);
    float var = stats[128 + f] * (1.0f / N_NODES) - m * m;
    float sc = g1[f] * rsqrtf(var + EPS);
    scale1[f] = sc;
    shift1[f] = be1[f] - m * sc;
}

// gnn_batch is sorted: per-graph node ranges via binary search
__global__ __launch_bounds__(1024) void graph_bounds_kernel(const int* __restrict__ batch,
                                                            int* __restrict__ gstart) {
    int g = threadIdx.x;
    int lo = 0, hi = N_NODES;
    while (lo < hi) {
        int mid = (lo + hi) >> 1;
        if (batch[mid] < g) lo = mid + 1; else hi = mid;
    }
    gstart[g] = lo;
    if (g == 0) gstart[N_GRAPHS] = N_NODES;
}

// pooled[g] = mean over rows of relu(agg*scale1+shift1); one wave per graph
__global__ __launch_bounds__(256) void pool_gather_kernel(const float* __restrict__ agg,
                                                          const int* __restrict__ gstart,
                                                          const float* __restrict__ scale1,
                                                          const float* __restrict__ shift1,
                                                          float* __restrict__ pooled) {
    int g = (blockIdx.x * 256 + threadIdx.x) >> 6;
    int lane = threadIdx.x & 63;
    if (g >= N_GRAPHS) return;
    int r0 = gstart[g], r1 = gstart[g + 1];
    int f = lane * 2;
    float2 sc = *(const float2*)(scale1 + f);
    float2 sh = *(const float2*)(shift1 + f);
    float2 acc = {0.f, 0.f};
    for (int r = r0; r < r1; ++r) {
        float2 a = *(const float2*)(agg + (size_t)r * 128 + f);
        acc.x += fmaxf(a.x * sc.x + sh.x, 0.f);
        acc.y += fmaxf(a.y * sc.y + sh.y, 0.f);
    }
    float inv = 1.0f / fmaxf((float)(r1 - r0), 1.0f);
    float2 o; o.x = acc.x * inv; o.y = acc.y * inv;
    *(float2*)(pooled + (size_t)g * 128 + f) = o;
}

// t1 = pooled @ W_lin1 + b ; stats1 += (sum, sumsq)
__global__ __launch_bounds__(256) void lin1_kernel(const float* __restrict__ pooled,
                                                   const float* __restrict__ W,
                                                   const float* __restrict__ bias,
                                                   float* __restrict__ t1,
                                                   float* __restrict__ stats1) {
    __shared__ float ls[256], ls2[256];
    int tid = threadIdx.x;
    int r = blockIdx.x * 4 + (tid >> 6);
    int c = tid & 63;
    float acc = bias[c];
    const float* srow = pooled + (size_t)r * 128;
#pragma unroll 8
    for (int k = 0; k < 128; ++k)
        acc += srow[k] * W[k * 64 + c];
    t1[r * 64 + c] = acc;
    ls[tid] = acc; ls2[tid] = acc * acc;
    __syncthreads();
    if (tid < 64) {
        float s = ls[tid] + ls[tid + 64] + ls[tid + 128] + ls[tid + 192];
        float q = ls2[tid] + ls2[tid + 64] + ls2[tid + 128] + ls2[tid + 192];
        unsafeAtomicAdd(&stats1[c], s);
        unsafeAtomicAdd(&stats1[64 + c], q);
    }
}

// t2 = relu(bn(t1; g2,be2)) @ W_lin2 + b ; stats2
__global__ __launch_bounds__(256) void lin2_kernel(const float* __restrict__ t1,
                                                   const float* __restrict__ stats1,
                                                   const float* __restrict__ g,
                                                   const float* __restrict__ be,
                                                   const float* __restrict__ W,
                                                   const float* __restrict__ bias,
                                                   float* __restrict__ t2,
                                                   float* __restrict__ stats2) {
    __shared__ float sc[64], sh[64];
    __shared__ float ls[256], ls2[256];
    int tid = threadIdx.x;
    if (tid < 64) {
        float m = stats1[tid] * (1.0f / BSZ);
        float var = stats1[64 + tid] * (1.0f / BSZ) - m * m;
        float s = g[tid] * rsqrtf(var + EPS);
        sc[tid] = s; sh[tid] = be[tid] - m * s;
    }
    __syncthreads();
    int r = blockIdx.x * 4 + (tid >> 6);
    int c = tid & 63;
    float acc = bias[c];
    const float* row = t1 + (size_t)r * 64;
#pragma unroll 8
    for (int k = 0; k < 64; ++k) {
        float z = fmaxf(row[k] * sc[k] + sh[k], 0.f);
        acc += z * W[k * 64 + c];
    }
    t2[r * 64 + c] = acc;
    ls[tid] = acc; ls2[tid] = acc * acc;
    __syncthreads();
    if (tid < 64) {
        float s = ls[tid] + ls[tid + 64] + ls[tid + 128] + ls[tid + 192];
        float q = ls2[tid] + ls2[tid + 64] + ls2[tid + 128] + ls2[tid + 192];
        unsafeAtomicAdd(&stats2[c], s);
        unsafeAtomicAdd(&stats2[64 + c], q);
    }
}

// t4 = concat(x, bn(t2;g3,be3)[masks]) @ W_fc1 + b ; stats4
__global__ __launch_bounds__(1024) void fc1_kernel(const float* __restrict__ x,
                                                   const int* __restrict__ masks,
                                                   const float* __restrict__ t2,
                                                   const float* __restrict__ stats2,
                                                   const float* __restrict__ g3,
                                                   const float* __restrict__ be3,
                                                   const float* __restrict__ W,
                                                   const float* __restrict__ bias,
                                                   float* __restrict__ t4,
                                                   float* __restrict__ stats4) {
    __shared__ float sc[64], sh[64];
    __shared__ float cat[4][128];
    __shared__ float ls[1024], ls2[1024];
    int tid = threadIdx.x;
    if (tid < 64) {
        float m = stats2[tid] * (1.0f / BSZ);
        float var = stats2[64 + tid] * (1.0f / BSZ) - m * m;
        float s = g3[tid] * rsqrtf(var + EPS);
        sc[tid] = s; sh[tid] = be3[tid] - m * s;
    }
    __syncthreads();
    int r0 = blockIdx.x * 4;
    if (tid < 512) {
        int i = tid >> 7;
        int k = tid & 127;
        int r = r0 + i;
        float v;
        if (k < 64) {
            v = x[r * 64 + k];
        } else {
            int mrow = masks[r];
            int kk = k - 64;
            v = t2[mrow * 64 + kk] * sc[kk] + sh[kk];
        }
        cat[i][k] = v;
    }
    __syncthreads();
    int i = tid >> 8;
    int c = tid & 255;
    float acc = bias[c];
#pragma unroll 8
    for (int k = 0; k < 128; ++k)
        acc += cat[i][k] * W[k * 256 + c];
    t4[(size_t)(r0 + i) * 256 + c] = acc;
    ls[tid] = acc; ls2[tid] = acc * acc;
    __syncthreads();
    if (tid < 256) {
        float s = ls[tid] + ls[tid + 256] + ls[tid + 512] + ls[tid + 768];
        float q = ls2[tid] + ls2[tid + 256] + ls2[tid + 512] + ls2[tid + 768];
        unsafeAtomicAdd(&stats4[c], s);
        unsafeAtomicAdd(&stats4[256 + c], q);
    }
}

// t5 = (relu(bn(t4;g4,be4))^2) @ W_fc2 + b ; stats5
__global__ __launch_bounds__(256) void fc2_kernel(const float* __restrict__ t4,
                                                  const float* __restrict__ stats4,
                                                  const float* __restrict__ g4,
                                                  const float* __restrict__ be4,
                                                  const float* __restrict__ W,
                                                  const float* __restrict__ bias,
                                                  float* __restrict__ t5,
                                                  float* __restrict__ stats5) {
    __shared__ float sc[256], sh[256];
    __shared__ float ls[256], ls2[256];
    int tid = threadIdx.x;
    {
        float m = stats4[tid] * (1.0f / BSZ);
        float var = stats4[256 + tid] * (1.0f / BSZ) - m * m;
        float s = g4[tid] * rsqrtf(var + EPS);
        sc[tid] = s; sh[tid] = be4[tid] - m * s;
    }
    __syncthreads();
    int r = blockIdx.x * 4 + (tid >> 6);
    int c = tid & 63;
    float acc = bias[c];
    const float* row = t4 + (size_t)r * 256;
#pragma unroll 8
    for (int k = 0; k < 256; ++k) {
        float z = fmaxf(row[k] * sc[k] + sh[k], 0.f);
        z *= z;
        acc += z * W[k * 64 + c];
    }
    t5[r * 64 + c] = acc;
    ls[tid] = acc; ls2[tid] = acc * acc;
    __syncthreads();
    if (tid < 64) {
        float s = ls[tid] + ls[tid + 64] + ls[tid + 128] + ls[tid + 192];
        float q = ls2[tid] + ls2[tid + 64] + ls2[tid + 128] + ls2[tid + 192];
        unsafeAtomicAdd(&stats5[c], s);
        unsafeAtomicAdd(&stats5[64 + c], q);
    }
}

// out = ((relu(bn(t5;g5,be5)))^4) @ W_fc3 + b
__global__ __launch_bounds__(256) void fc3_kernel(const float* __restrict__ t5,
                                                  const float* __restrict__ stats5,
                                                  const float* __restrict__ g5,
                                                  const float* __restrict__ be5,
                                                  const float* __restrict__ W,
                                                  const float* __restrict__ bias,
                                                  float* __restrict__ out) {
    __shared__ float sc[64], sh[64];
    int tid = threadIdx.x;
    if (tid < 64) {
        float m = stats5[tid] * (1.0f / BSZ);
        float var = stats5[64 + tid] * (1.0f / BSZ) - m * m;
        float s = g5[tid] * rsqrtf(var + EPS);
        sc[tid] = s; sh[tid] = be5[tid] - m * s;
    }
    __syncthreads();
    int r = blockIdx.x * 256 + tid;
    float acc = bias[0];
    const float* row = t5 + (size_t)r * 64;
#pragma unroll
    for (int k = 0; k < 64; ++k) {
        float z = fmaxf(row[k] * sc[k] + sh[k], 0.f);
        z = z * z;
        z = z * z;
        acc += z * W[k];
    }
    out[r] = acc;
}

extern "C" void kernel_launch(void* const* d_in, const int* in_sizes, int n_in,
                              void* d_out, int out_size, void* d_ws, size_t ws_size,
                              hipStream_t stream) {
    const float* x      = (const float*)d_in[0];
    const int*   masks  = (const int*)d_in[1];
    const float* gnn_x  = (const float*)d_in[2];
    const int*   ei     = (const int*)d_in[3];
    const int*   gbatch = (const int*)d_in[4];
    const float* W_gcn  = (const float*)d_in[5];
    const float* b_gcn  = (const float*)d_in[6];
    const float* g1     = (const float*)d_in[7];
    const float* be1    = (const float*)d_in[8];
    const float* W_lin1 = (const float*)d_in[9];
    const float* b_lin1 = (const float*)d_in[10];
    const float* g2     = (const float*)d_in[11];
    const float* be2    = (const float*)d_in[12];
    const float* W_lin2 = (const float*)d_in[13];
    const float* b_lin2 = (const float*)d_in[14];
    const float* g3     = (const float*)d_in[15];
    const float* be3    = (const float*)d_in[16];
    const float* W_fc1  = (const float*)d_in[17];
    const float* b_fc1  = (const float*)d_in[18];
    const float* g4     = (const float*)d_in[19];
    const float* be4    = (const float*)d_in[20];
    const float* W_fc2  = (const float*)d_in[21];
    const float* b_fc2  = (const float*)d_in[22];
    const float* g5     = (const float*)d_in[23];
    const float* be5    = (const float*)d_in[24];
    const float* W_fc3  = (const float*)d_in[25];
    const float* b_fc3  = (const float*)d_in[26];

    float* ws = (float*)d_ws;
    float* bnagg  = ws + WS_BNAGG;
    float* stats1 = ws + WS_STATS1;
    float* stats2 = ws + WS_STATS2;
    float* stats4 = ws + WS_STATS4;
    float* stats5 = ws + WS_STATS5;
    int*   deg    = (int*)(ws + WS_DEG);
    int*   incl   = (int*)(ws + WS_INCL);
    int*   part   = (int*)(ws + WS_PARTIAL);
    int*   poff   = (int*)(ws + WS_POFF);
    int*   rowptr = (int*)(ws + WS_ROWPTR);
    int*   cursor = (int*)(ws + WS_CURSOR);
    float* dis    = ws + WS_DIS;
    int*   csrc   = (int*)(ws + WS_CSRC);
    float* scale1 = ws + WS_SCALE1;
    float* shift1 = ws + WS_SHIFT1;
    int*   gstart = (int*)(ws + WS_GSTART);
    float* aggx   = ws + WS_AGGX;
    float* agg    = ws + WS_AGG;
    float* pooled = ws + WS_POOLED;
    float* t1     = ws + WS_T1;
    float* t2     = ws + WS_T2;
    float* t4     = ws + WS_T4;
    float* t5     = ws + WS_T5;
    float* out    = (float*)d_out;

    zero_kernel<<<128, 256, 0, stream>>>(ws, WS_ZTOTAL);
    deg_count_kernel<<<(N_EDGES + 255) / 256, 256, 0, stream>>>(ei + N_EDGES, deg);
    scan1_kernel<<<SCAN_NB, 256, 0, stream>>>(deg, incl, part);
    scan2_kernel<<<1, 512, 0, stream>>>(part, poff);
    scan3_kernel<<<SCAN_NB, 256, 0, stream>>>(deg, incl, poff, rowptr, cursor, dis);
    csr_fill_kernel<<<(N_EDGES + 255) / 256, 256, 0, stream>>>(ei, cursor, csrc);
    gather_aggx_kernel<<<(N_NODES * 64 + 255) / 256, 256, 0, stream>>>(gnn_x, rowptr, csrc, dis, aggx);
    gemm_agg_kernel<<<N_NODES / 16, 256, 0, stream>>>(aggx, W_gcn, b_gcn, agg);
    bnagg_stats_kernel<<<512, 256, 0, stream>>>(agg, bnagg);
    bn1_fold_kernel<<<1, 128, 0, stream>>>(bnagg, g1, be1, scale1, shift1);
    graph_bounds_kernel<<<1, 1024, 0, stream>>>(gbatch, gstart);
    pool_gather_kernel<<<(N_GRAPHS * 64 + 255) / 256, 256, 0, stream>>>(agg, gstart, scale1, shift1, pooled);
    lin1_kernel<<<256, 256, 0, stream>>>(pooled, W_lin1, b_lin1, t1, stats1);
    lin2_kernel<<<256, 256, 0, stream>>>(t1, stats1, g2, be2, W_lin2, b_lin2, t2, stats2);
    fc1_kernel<<<256, 1024, 0, stream>>>(x, masks, t2, stats2, g3, be3, W_fc1, b_fc1, t4, stats4);
    fc2_kernel<<<256, 256, 0, stream>>>(t4, stats4, g4, be4, W_fc2, b_fc2, t5, stats5);
    fc3_kernel<<<4, 256, 0, stream>>>(t5, stats5, g5, be5, W_fc3, b_fc3, out);
}